// Round 4
// baseline (106.547 us; speedup 1.0000x reference)
//
#include <hip/hip_runtime.h>
#include <hip/hip_cooperative_groups.h>
#include <float.h>

namespace cg = cooperative_groups;

static constexpr int H    = 2048;
static constexpr int Wd   = 2048;
static constexpr int NPIX = H * Wd;
static constexpr int BT   = 256;               // threads per block
static constexpr int N4   = NPIX / 4;
static constexpr int NB   = 1024;              // blocks (co-resident: 4 waves/block)
static constexpr int ITER = N4 / (NB * BT);    // == 4, exact

// ws layout (floats, SoA): ws[s*NB + b] = block b's partial for slot s.
// slots: [0..2] sparse min {x*z, y*z, z} (UNSCALED by 1/fx,1/fy),
//        [3..5] sparse max, [6..8] dense min, [9..11] dense max

__global__ __launch_bounds__(BT) void fused_depth_scale_kernel(
    const float* __restrict__ dense,
    const float* __restrict__ sparse,
    const int*   __restrict__ mask,
    const float* __restrict__ intr,
    float* __restrict__ ws,
    float* __restrict__ out)
{
    const float cx = intr[2], cy = intr[3];
    const float qnan = __uint_as_float(0x7FC00000u);

    const float4* d4 = (const float4*)dense;
    const float4* s4 = (const float4*)sparse;
    const int4*   m4 = (const int4*)mask;

    const int tid = blockIdx.x * BT + threadIdx.x;

    float loc[12];
#pragma unroll
    for (int s = 0; s < 12; ++s) loc[s] = ((s % 6) < 3) ? FLT_MAX : -FLT_MAX;

    float4 dv[ITER];   // dense pixels held in registers across the grid sync

#pragma unroll
    for (int k = 0; k < ITER; ++k) {
        const int i = tid + k * (NB * BT);
        int4   mv = m4[i];
        dv[k]     = d4[i];
        float4 sv = s4[i];
        int base = i << 2;                      // 2048 % 4 == 0: row never split
        float yc = (float)(base >> 11) - cy;    // row index - cy
        float xf = (float)(base & 2047);

        const int   mm[4] = { mv.x, mv.y, mv.z, mv.w };
        const float dd[4] = { dv[k].x, dv[k].y, dv[k].z, dv[k].w };
        const float ss[4] = { sv.x, sv.y, sv.z, sv.w };

#pragma unroll
        for (int j = 0; j < 4; ++j) {
            // Branchless: NaN sentinel for masked-out pixels; v_min/v_max
            // (IEEE) drop the NaN operand, so masked lanes are no-ops.
            float sd = (mm[j] != 0) ? ss[j] : qnan;
            float de = (mm[j] != 0) ? dd[j] : qnan;
            float xc = xf + (float)j - cx;
            float spx = xc * sd;
            float spy = yc * sd;
            float dpx = xc * de;
            float dpy = yc * de;
            loc[0] = fminf(loc[0], spx); loc[3]  = fmaxf(loc[3],  spx);
            loc[1] = fminf(loc[1], spy); loc[4]  = fmaxf(loc[4],  spy);
            loc[2] = fminf(loc[2], sd ); loc[5]  = fmaxf(loc[5],  sd );
            loc[6] = fminf(loc[6], dpx); loc[9]  = fmaxf(loc[9],  dpx);
            loc[7] = fminf(loc[7], dpy); loc[10] = fmaxf(loc[10], dpy);
            loc[8] = fminf(loc[8], de ); loc[11] = fmaxf(loc[11], de );
        }
    }

    // wave-64 butterfly reduction
#pragma unroll
    for (int off = 32; off > 0; off >>= 1) {
#pragma unroll
        for (int s = 0; s < 12; ++s) {
            float o = __shfl_xor(loc[s], off, 64);
            loc[s] = ((s % 6) < 3) ? fminf(loc[s], o) : fmaxf(loc[s], o);
        }
    }

    __shared__ float red[4][12];
    __shared__ float ratio_sh;
    const int lane = threadIdx.x & 63;
    const int wid  = threadIdx.x >> 6;
    if (lane == 0) {
#pragma unroll
        for (int s = 0; s < 12; ++s) red[wid][s] = loc[s];
    }
    __syncthreads();

    if (threadIdx.x < 12) {
        int s = threadIdx.x;
        bool is_min = (s % 6) < 3;
        float v = red[0][s];
#pragma unroll
        for (int w = 1; w < 4; ++w)
            v = is_min ? fminf(v, red[w][s]) : fmaxf(v, red[w][s]);
        ws[s * NB + blockIdx.x] = v;   // plain store, no atomics
    }

    cg::this_grid().sync();

    // Phase 2: every block redundantly reduces the NB x 12 partials
    // (48 KB, L2-served broadcast), computes the ratio.
    float loc2[12];
#pragma unroll
    for (int s = 0; s < 12; ++s) loc2[s] = ((s % 6) < 3) ? FLT_MAX : -FLT_MAX;

    for (int b = threadIdx.x; b < NB; b += BT) {
#pragma unroll
        for (int s = 0; s < 12; ++s) {
            float p = ws[s * NB + b];
            loc2[s] = ((s % 6) < 3) ? fminf(loc2[s], p) : fmaxf(loc2[s], p);
        }
    }

#pragma unroll
    for (int off = 32; off > 0; off >>= 1) {
#pragma unroll
        for (int s = 0; s < 12; ++s) {
            float o = __shfl_xor(loc2[s], off, 64);
            loc2[s] = ((s % 6) < 3) ? fminf(loc2[s], o) : fmaxf(loc2[s], o);
        }
    }

    if (lane == 0) {
#pragma unroll
        for (int s = 0; s < 12; ++s) red[wid][s] = loc2[s];
    }
    __syncthreads();

    if (threadIdx.x == 0) {
        float fin[12];
#pragma unroll
        for (int s = 0; s < 12; ++s) {
            bool is_min = (s % 6) < 3;
            float v = red[0][s];
#pragma unroll
            for (int w = 1; w < 4; ++w)
                v = is_min ? fminf(v, red[w][s]) : fmaxf(v, red[w][s]);
            fin[s] = v;
        }
        const float inv_fx = 1.0f / intr[0], inv_fy = 1.0f / intr[1];
        float sx = (fin[3]  - fin[0]) * inv_fx;
        float sy = (fin[4]  - fin[1]) * inv_fy;
        float sz =  fin[5]  - fin[2];
        float dx = (fin[9]  - fin[6]) * inv_fx;
        float dy = (fin[10] - fin[7]) * inv_fy;
        float dz =  fin[11] - fin[8];
        ratio_sh = sqrtf(sx*sx + sy*sy + sz*sz) / sqrtf(dx*dx + dy*dy + dz*dz);
    }
    __syncthreads();

    // Phase 3: scale the register-held dense values, store.
    const float r = ratio_sh;
    float4* o4 = (float4*)out;
#pragma unroll
    for (int k = 0; k < ITER; ++k) {
        const int i = tid + k * (NB * BT);
        float4 v = dv[k];
        o4[i] = make_float4(v.x * r, v.y * r, v.z * r, v.w * r);
    }
    if (blockIdx.x == 0 && threadIdx.x == 0) out[NPIX] = 1.0f;  // std
}

extern "C" void kernel_launch(void* const* d_in, const int* in_sizes, int n_in,
                              void* d_out, int out_size, void* d_ws, size_t ws_size,
                              hipStream_t stream) {
    const float* dense  = (const float*)d_in[0];  // depth_estimations
    const float* sparse = (const float*)d_in[1];  // sparse_depths
    const int*   mask   = (const int*)d_in[2];    // sparse_depth_masks
    const float* intr   = (const float*)d_in[3];  // intrinsics

    float* out  = (float*)d_out;
    float* ws_f = (float*)d_ws;

    void* args[] = { (void*)&dense, (void*)&sparse, (void*)&mask,
                     (void*)&intr, (void*)&ws_f, (void*)&out };
    hipLaunchCooperativeKernel((const void*)fused_depth_scale_kernel,
                               dim3(NB), dim3(BT), args, 0, stream);
}

// Round 5
// 71.806 us; speedup vs baseline: 1.4838x; 1.4838x over previous
//
#include <hip/hip_runtime.h>
#include <float.h>

static constexpr int H    = 2048;
static constexpr int Wd   = 2048;
static constexpr int NPIX = H * Wd;
static constexpr int BT   = 256;               // threads per block
static constexpr int NB   = 512;               // blocks; 2/CU -> co-residency guaranteed
static constexpr int N4   = NPIX / 4;
static constexpr int ITER = N4 / (NB * BT);    // == 8, exact

// ws layout: float partials ws[s*NB + b], s in [0,12); then uint counter at ws[12*NB].
// slots: [0..2] sparse min {x*z, y*z, z} (unscaled), [3..5] sparse max,
//        [6..8] dense min, [9..11] dense max.

__global__ __launch_bounds__(BT, 2) void fused_depth_scale_kernel(
    const float* __restrict__ dense,
    const float* __restrict__ sparse,
    const int*   __restrict__ mask,
    const float* __restrict__ intr,
    float* __restrict__ ws,
    unsigned int* __restrict__ cnt,   // zeroed via hipMemsetAsync before each launch
    float* __restrict__ out)
{
    const float cx = intr[2], cy = intr[3];
    const float qnan = __uint_as_float(0x7FC00000u);

    const float4* d4 = (const float4*)dense;
    const float4* s4 = (const float4*)sparse;
    const int4*   m4 = (const int4*)mask;

    const int tid = blockIdx.x * BT + threadIdx.x;

    float loc[12];
#pragma unroll
    for (int s = 0; s < 12; ++s) loc[s] = ((s % 6) < 3) ? FLT_MAX : -FLT_MAX;

    float4 dv[ITER];   // dense pixels held in registers through the device sync

    // ---- Phase 1: masked bbox reduce (branchless NaN-sentinel), batched loads ----
#pragma unroll
    for (int r = 0; r < 2; ++r) {
        int4   mv[4];
        float4 sv[4];
#pragma unroll
        for (int q = 0; q < 4; ++q) {               // 12 loads in flight per round
            const int k = r * 4 + q;
            const int i = tid + k * (NB * BT);
            mv[q] = m4[i];
            sv[q] = s4[i];
            dv[k] = d4[i];
        }
#pragma unroll
        for (int q = 0; q < 4; ++q) {
            const int k = r * 4 + q;
            const int i = tid + k * (NB * BT);
            const int base = i << 2;                 // 2048 % 4 == 0: row never split
            const float yc = (float)(base >> 11) - cy;
            const float xf = (float)(base & 2047);
            const int   mm[4] = { mv[q].x, mv[q].y, mv[q].z, mv[q].w };
            const float dd[4] = { dv[k].x, dv[k].y, dv[k].z, dv[k].w };
            const float ss[4] = { sv[q].x, sv[q].y, sv[q].z, sv[q].w };
#pragma unroll
            for (int j = 0; j < 4; ++j) {
                // NaN sentinel: v_min/v_max (IEEE) drop the NaN operand.
                float sd = (mm[j] != 0) ? ss[j] : qnan;
                float de = (mm[j] != 0) ? dd[j] : qnan;
                float xc = xf + (float)j - cx;
                float spx = xc * sd;
                float spy = yc * sd;
                float dpx = xc * de;
                float dpy = yc * de;
                loc[0] = fminf(loc[0], spx); loc[3]  = fmaxf(loc[3],  spx);
                loc[1] = fminf(loc[1], spy); loc[4]  = fmaxf(loc[4],  spy);
                loc[2] = fminf(loc[2], sd ); loc[5]  = fmaxf(loc[5],  sd );
                loc[6] = fminf(loc[6], dpx); loc[9]  = fmaxf(loc[9],  dpx);
                loc[7] = fminf(loc[7], dpy); loc[10] = fmaxf(loc[10], dpy);
                loc[8] = fminf(loc[8], de ); loc[11] = fmaxf(loc[11], de );
            }
        }
    }

    // wave-64 butterfly
#pragma unroll
    for (int off = 32; off > 0; off >>= 1) {
#pragma unroll
        for (int s = 0; s < 12; ++s) {
            float o = __shfl_xor(loc[s], off, 64);
            loc[s] = ((s % 6) < 3) ? fminf(loc[s], o) : fmaxf(loc[s], o);
        }
    }

    __shared__ float red[4][12];
    __shared__ float ratio_sh;
    const int lane = threadIdx.x & 63;
    const int wid  = threadIdx.x >> 6;
    if (lane == 0) {
#pragma unroll
        for (int s = 0; s < 12; ++s) red[wid][s] = loc[s];
    }
    __syncthreads();

    // publish per-block partials: agent-scope write-through stores
    if (threadIdx.x < 12) {
        const int s = threadIdx.x;
        const bool is_min = (s % 6) < 3;
        float v = red[0][s];
#pragma unroll
        for (int w = 1; w < 4; ++w)
            v = is_min ? fminf(v, red[w][s]) : fmaxf(v, red[w][s]);
        __hip_atomic_store(&ws[s * NB + blockIdx.x], v,
                           __ATOMIC_RELAXED, __HIP_MEMORY_SCOPE_AGENT);
    }
    __syncthreads();   // drains vmcnt -> partial stores performed at coherence point

    // ---- Device-wide sync: arrive + backoff spin (one poller per block) ----
    if (threadIdx.x == 0) {
        __hip_atomic_fetch_add(cnt, 1u, __ATOMIC_RELEASE, __HIP_MEMORY_SCOPE_AGENT);
        while (__hip_atomic_load(cnt, __ATOMIC_ACQUIRE, __HIP_MEMORY_SCOPE_AGENT) < (unsigned)NB)
            __builtin_amdgcn_s_sleep(32);   // ~0.85 us between polls
    }
    __syncthreads();
    // per-thread acquire: invalidate stale L1/L2 lines so plain loads below are fresh
    __builtin_amdgcn_fence(__ATOMIC_ACQUIRE, "agent");

    // ---- Phase 2: every block reduces the 12 x NB partials (24 KB, LLC-served) ----
    float loc2[12];
#pragma unroll
    for (int s = 0; s < 12; ++s) loc2[s] = ((s % 6) < 3) ? FLT_MAX : -FLT_MAX;

    if (threadIdx.x < NB / 4) {              // 128 threads x float4 = 512 partials/slot
        const float4* p4 = (const float4*)ws;
#pragma unroll
        for (int s = 0; s < 12; ++s) {
            float4 p = p4[(s * NB) / 4 + threadIdx.x];
            if ((s % 6) < 3)
                loc2[s] = fminf(fminf(p.x, p.y), fminf(p.z, p.w));
            else
                loc2[s] = fmaxf(fmaxf(p.x, p.y), fmaxf(p.z, p.w));
        }
    }

#pragma unroll
    for (int off = 32; off > 0; off >>= 1) {
#pragma unroll
        for (int s = 0; s < 12; ++s) {
            float o = __shfl_xor(loc2[s], off, 64);
            loc2[s] = ((s % 6) < 3) ? fminf(loc2[s], o) : fmaxf(loc2[s], o);
        }
    }

    if (lane == 0) {
#pragma unroll
        for (int s = 0; s < 12; ++s) red[wid][s] = loc2[s];
    }
    __syncthreads();

    if (threadIdx.x == 0) {
        float fin[12];
#pragma unroll
        for (int s = 0; s < 12; ++s) {
            const bool is_min = (s % 6) < 3;
            float v = red[0][s];
#pragma unroll
            for (int w = 1; w < 4; ++w)
                v = is_min ? fminf(v, red[w][s]) : fmaxf(v, red[w][s]);
            fin[s] = v;
        }
        const float inv_fx = 1.0f / intr[0], inv_fy = 1.0f / intr[1];
        float sx = (fin[3]  - fin[0]) * inv_fx;
        float sy = (fin[4]  - fin[1]) * inv_fy;
        float sz =  fin[5]  - fin[2];
        float dx = (fin[9]  - fin[6]) * inv_fx;
        float dy = (fin[10] - fin[7]) * inv_fy;
        float dz =  fin[11] - fin[8];
        ratio_sh = sqrtf(sx*sx + sy*sy + sz*sz) / sqrtf(dx*dx + dy*dy + dz*dz);
    }
    __syncthreads();

    // ---- Phase 3: scale register-held dense, store ----
    const float r2 = ratio_sh;
    float4* o4 = (float4*)out;
#pragma unroll
    for (int k = 0; k < ITER; ++k) {
        const int i = tid + k * (NB * BT);
        float4 v = dv[k];
        o4[i] = make_float4(v.x * r2, v.y * r2, v.z * r2, v.w * r2);
    }
    if (blockIdx.x == 0 && threadIdx.x == 0) out[NPIX] = 1.0f;  // std
}

extern "C" void kernel_launch(void* const* d_in, const int* in_sizes, int n_in,
                              void* d_out, int out_size, void* d_ws, size_t ws_size,
                              hipStream_t stream) {
    const float* dense  = (const float*)d_in[0];  // depth_estimations
    const float* sparse = (const float*)d_in[1];  // sparse_depths
    const int*   mask   = (const int*)d_in[2];    // sparse_depth_masks
    const float* intr   = (const float*)d_in[3];  // intrinsics

    float*        out  = (float*)d_out;
    float*        ws_f = (float*)d_ws;
    unsigned int* cnt  = (unsigned int*)(ws_f + 12 * NB);

    hipMemsetAsync((void*)cnt, 0, sizeof(unsigned int), stream);  // graph-capturable node
    fused_depth_scale_kernel<<<NB, BT, 0, stream>>>(dense, sparse, mask, intr,
                                                    ws_f, cnt, out);
}

// Round 6
// 26.261 us; speedup vs baseline: 4.0572x; 2.7343x over previous
//
#include <hip/hip_runtime.h>
#include <float.h>

static constexpr int H    = 2048;
static constexpr int Wd   = 2048;
static constexpr int NPIX = H * Wd;
static constexpr int BT   = 256;                 // threads per block
static constexpr int N4   = NPIX / 4;

static constexpr int NB1   = 1024;               // stage-1 blocks
static constexpr int ITER1 = N4 / (NB1 * BT);    // == 4, exact
static constexpr int NB2   = 2048;               // stage-2 blocks
static constexpr int ITER2 = N4 / (NB2 * BT);    // == 2, exact

// ws layout (floats, SoA): ws[s*NB1 + b] = block b's partial for slot s.
// slots: [0..2] sparse min {x*z, y*z, z} (UNSCALED by 1/fx,1/fy),
//        [3..5] sparse max, [6..8] dense min, [9..11] dense max.
// All 12*NB1 slots are unconditionally rewritten every call (deterministic).

__global__ __launch_bounds__(BT) void reduce_bbox_kernel(
    const float* __restrict__ dense,
    const float* __restrict__ sparse,
    const int*   __restrict__ mask,
    const float* __restrict__ intr,
    float* __restrict__ ws)
{
    const float cx = intr[2], cy = intr[3];
    const float qnan = __uint_as_float(0x7FC00000u);

    const float4* d4 = (const float4*)dense;
    const float4* s4 = (const float4*)sparse;
    const int4*   m4 = (const int4*)mask;

    const int tid = blockIdx.x * BT + threadIdx.x;

    float loc[12];
#pragma unroll
    for (int s = 0; s < 12; ++s) loc[s] = ((s % 6) < 3) ? FLT_MAX : -FLT_MAX;

    // Issue ALL 12 vector loads up front (max MLP), then consume.
    int4   mv[ITER1];
    float4 sv[ITER1];
    float4 dv[ITER1];
#pragma unroll
    for (int k = 0; k < ITER1; ++k) {
        const int i = tid + k * (NB1 * BT);
        mv[k] = m4[i];
        sv[k] = s4[i];
        dv[k] = d4[i];
    }

#pragma unroll
    for (int k = 0; k < ITER1; ++k) {
        const int i = tid + k * (NB1 * BT);
        const int base = i << 2;                 // 2048 % 4 == 0: row never split
        const float yc = (float)(base >> 11) - cy;
        const float xf = (float)(base & 2047);
        const int   mm[4] = { mv[k].x, mv[k].y, mv[k].z, mv[k].w };
        const float dd[4] = { dv[k].x, dv[k].y, dv[k].z, dv[k].w };
        const float ss[4] = { sv[k].x, sv[k].y, sv[k].z, sv[k].w };
#pragma unroll
        for (int j = 0; j < 4; ++j) {
            // Branchless: NaN sentinel for masked-out pixels; v_min/v_max
            // (IEEE) return the non-NaN operand -> masked lanes are no-ops.
            float sd = (mm[j] != 0) ? ss[j] : qnan;
            float de = (mm[j] != 0) ? dd[j] : qnan;
            float xc = xf + (float)j - cx;
            float spx = xc * sd;
            float spy = yc * sd;
            float dpx = xc * de;
            float dpy = yc * de;
            loc[0] = fminf(loc[0], spx); loc[3]  = fmaxf(loc[3],  spx);
            loc[1] = fminf(loc[1], spy); loc[4]  = fmaxf(loc[4],  spy);
            loc[2] = fminf(loc[2], sd ); loc[5]  = fmaxf(loc[5],  sd );
            loc[6] = fminf(loc[6], dpx); loc[9]  = fmaxf(loc[9],  dpx);
            loc[7] = fminf(loc[7], dpy); loc[10] = fmaxf(loc[10], dpy);
            loc[8] = fminf(loc[8], de ); loc[11] = fmaxf(loc[11], de );
        }
    }

    // wave-64 butterfly
#pragma unroll
    for (int off = 32; off > 0; off >>= 1) {
#pragma unroll
        for (int s = 0; s < 12; ++s) {
            float o = __shfl_xor(loc[s], off, 64);
            loc[s] = ((s % 6) < 3) ? fminf(loc[s], o) : fmaxf(loc[s], o);
        }
    }

    __shared__ float red[4][12];
    const int lane = threadIdx.x & 63;
    const int wid  = threadIdx.x >> 6;
    if (lane == 0) {
#pragma unroll
        for (int s = 0; s < 12; ++s) red[wid][s] = loc[s];
    }
    __syncthreads();

    if (threadIdx.x < 12) {
        const int s = threadIdx.x;
        const bool is_min = (s % 6) < 3;
        float v = red[0][s];
#pragma unroll
        for (int w = 1; w < 4; ++w)
            v = is_min ? fminf(v, red[w][s]) : fmaxf(v, red[w][s]);
        ws[s * NB1 + blockIdx.x] = v;   // plain store, no atomics
    }
}

// Stage 2: issue dense loads FIRST, hide the 48 KB partial re-reduce under
// them, then scale and store. NB1/4 == BT, so every thread loads exactly one
// float4 per slot: zero divergence, fully coalesced.
__global__ __launch_bounds__(BT) void finalize_scale_kernel(
    const float* __restrict__ dense,
    const float* __restrict__ intr,
    const float* __restrict__ ws,
    float* __restrict__ out)
{
    const int tid = blockIdx.x * BT + threadIdx.x;
    const float4* d4 = (const float4*)dense;

    // dense loads in flight while we reduce partials
    float4 v0 = d4[tid];
    float4 v1 = d4[tid + NB2 * BT];

    static_assert(NB1 / 4 == BT, "one float4 per thread per slot");
    const float4* p4 = (const float4*)ws;
    float loc[12];
#pragma unroll
    for (int s = 0; s < 12; ++s) {
        float4 p = p4[s * BT + threadIdx.x];
        if ((s % 6) < 3)
            loc[s] = fminf(fminf(p.x, p.y), fminf(p.z, p.w));
        else
            loc[s] = fmaxf(fmaxf(p.x, p.y), fmaxf(p.z, p.w));
    }

#pragma unroll
    for (int off = 32; off > 0; off >>= 1) {
#pragma unroll
        for (int s = 0; s < 12; ++s) {
            float o = __shfl_xor(loc[s], off, 64);
            loc[s] = ((s % 6) < 3) ? fminf(loc[s], o) : fmaxf(loc[s], o);
        }
    }

    __shared__ float red[4][12];
    __shared__ float ratio_sh;
    const int lane = threadIdx.x & 63;
    const int wid  = threadIdx.x >> 6;
    if (lane == 0) {
#pragma unroll
        for (int s = 0; s < 12; ++s) red[wid][s] = loc[s];
    }
    __syncthreads();

    if (threadIdx.x == 0) {
        float fin[12];
#pragma unroll
        for (int s = 0; s < 12; ++s) {
            const bool is_min = (s % 6) < 3;
            float v = red[0][s];
#pragma unroll
            for (int w = 1; w < 4; ++w)
                v = is_min ? fminf(v, red[w][s]) : fmaxf(v, red[w][s]);
            fin[s] = v;
        }
        const float inv_fx = 1.0f / intr[0], inv_fy = 1.0f / intr[1];
        float sx = (fin[3]  - fin[0]) * inv_fx;
        float sy = (fin[4]  - fin[1]) * inv_fy;
        float sz =  fin[5]  - fin[2];
        float dx = (fin[9]  - fin[6]) * inv_fx;
        float dy = (fin[10] - fin[7]) * inv_fy;
        float dz =  fin[11] - fin[8];
        ratio_sh = sqrtf(sx*sx + sy*sy + sz*sz) / sqrtf(dx*dx + dy*dy + dz*dz);
    }
    __syncthreads();

    const float r = ratio_sh;
    float4* o4 = (float4*)out;
    o4[tid]            = make_float4(v0.x * r, v0.y * r, v0.z * r, v0.w * r);
    o4[tid + NB2 * BT] = make_float4(v1.x * r, v1.y * r, v1.z * r, v1.w * r);
    if (blockIdx.x == 0 && threadIdx.x == 0) out[NPIX] = 1.0f;  // std
}

extern "C" void kernel_launch(void* const* d_in, const int* in_sizes, int n_in,
                              void* d_out, int out_size, void* d_ws, size_t ws_size,
                              hipStream_t stream) {
    const float* dense  = (const float*)d_in[0];  // depth_estimations
    const float* sparse = (const float*)d_in[1];  // sparse_depths
    const int*   mask   = (const int*)d_in[2];    // sparse_depth_masks
    const float* intr   = (const float*)d_in[3];  // intrinsics

    float* out  = (float*)d_out;
    float* ws_f = (float*)d_ws;

    reduce_bbox_kernel<<<NB1, BT, 0, stream>>>(dense, sparse, mask, intr, ws_f);
    finalize_scale_kernel<<<NB2, BT, 0, stream>>>(dense, intr, ws_f, out);
}